// Round 2
// baseline (10269.569 us; speedup 1.0000x reference)
//
#include <hip/hip_runtime.h>

#define BB 256
#define SS 336
#define NT 431   // output time steps
#define NU 432   // total cell steps
#define NBLK 128 // 2 branch * 2 rowhalf * 32 colgroup

typedef __attribute__((ext_vector_type(8))) short bf16x8;
typedef __attribute__((ext_vector_type(16))) float f32x16;

// ---------------- ws layout (bytes) ----------------
// wfrag @ 0        : 8388608  (4 mats x [cg32][csub2][kb32][lane64] int4)
// hbuf  @ 8388608  : 1048576  ([par2][br2][rb8][kb32][lane64] int4)
// flags @ 9437184  : 8192     (128 blocks x 16 ints, 64B stride)
// xbuf  @ 9445376  : 2752512  ([br2][336][256] float4)
// M     @ 12197888 : 65536    ([2][2048][4] f32)
// bE    @ 12263424 : 16384
// bP    @ 12279808 : 16384

__device__ inline unsigned short f2bf(float f) {
    unsigned int u = __float_as_uint(f);
    unsigned int r = (u + 0x7fffu + ((u >> 16) & 1u)) >> 16;
    return (unsigned short)r;
}
__device__ inline float sigm(float x) { return 1.f / (1.f + __expf(-x)); }
__device__ inline float tanh_(float x) { return 2.f / (1.f + __expf(-2.f * x)) - 1.f; }

// f32 [2048][512] -> bf16 MFMA B-fragment order [mat][cg][csub][kb][lane] int4
__global__ void k_wfrag(const float* __restrict__ w0, const float* __restrict__ w1,
                        const float* __restrict__ w2, const float* __restrict__ w3,
                        unsigned short* __restrict__ wfrag) {
    int idx = blockIdx.x * 256 + threadIdx.x;      // 0 .. 524287
    int mat = idx >> 17;
    int t = idx & 131071;
    int lane = t & 63;
    int kb = (t >> 6) & 31;
    int csub = (t >> 11) & 1;
    int cg = t >> 12;
    const float* W = mat == 0 ? w0 : (mat == 1 ? w1 : (mat == 2 ? w2 : w3));
    int n_local = csub * 32 + (lane & 31);
    int n = (n_local >> 4) * 512 + cg * 16 + (n_local & 15);
    int k0 = kb * 16 + (lane >> 5) * 8;
    const float* src = W + n * 512 + k0;
    unsigned short us[8];
#pragma unroll
    for (int j = 0; j < 8; ++j) us[j] = f2bf(src[j]);
    int4 v;
    v.x = us[0] | (us[1] << 16); v.y = us[2] | (us[3] << 16);
    v.z = us[4] | (us[5] << 16); v.w = us[6] | (us[7] << 16);
    ((int4*)wfrag)[idx] = v;
}

__global__ void k_mbias(const float* __restrict__ lin_wih, const float* __restrict__ quat_wih,
                        const float* __restrict__ lin_enc_w, const float* __restrict__ quat_enc_w,
                        const float* __restrict__ lin_enc_b, const float* __restrict__ quat_enc_b,
                        const float* __restrict__ lin_bih, const float* __restrict__ lin_bhh,
                        const float* __restrict__ quat_bih, const float* __restrict__ quat_bhh,
                        float* __restrict__ M, float* __restrict__ bE, float* __restrict__ bP) {
    int gid = blockIdx.x * 256 + threadIdx.x;      // 0..4095
    int branch = gid >> 11;
    int n = gid & 2047;
    int nf = 3 + branch;
    const float* Wih = branch ? quat_wih : lin_wih;
    const float* We  = branch ? quat_enc_w : lin_enc_w;
    const float* be  = branch ? quat_enc_b : lin_enc_b;
    const float* bih = branch ? quat_bih : lin_bih;
    const float* bhh = branch ? quat_bhh : lin_bhh;
    float m[4] = {0.f, 0.f, 0.f, 0.f};
    float bs = 0.f;
    for (int j = 0; j < 512; ++j) {
        float w = Wih[n * 512 + j];
#pragma unroll
        for (int kf = 0; kf < 4; ++kf)
            if (kf < nf) m[kf] += w * We[j * nf + kf];
        bs += w * be[j];
    }
    float* Mp = M + (branch * 2048 + n) * 4;
#pragma unroll
    for (int kf = 0; kf < 4; ++kf) Mp[kf] = m[kf];
    bE[branch * 2048 + n] = bs + bih[n] + bhh[n];
    bP[branch * 2048 + n] = bih[n] + bhh[n];
}

// xbuf[branch][u][b] = float4 of x[b,u, branch*3 .. +nf)
__global__ void k_xprep(const float* __restrict__ x, float4* __restrict__ xbuf) {
    int gid = blockIdx.x * 256 + threadIdx.x;      // 0..172031
    int branch = gid / 86016;
    int rem = gid - branch * 86016;
    int u = rem >> 8;
    int b = rem & 255;
    int nf = 3 + branch;
    const float* xp = x + (b * SS + u) * 7 + branch * 3;
    float4 v = {0.f, 0.f, 0.f, 0.f};
    v.x = xp[0]; v.y = xp[1]; v.z = xp[2];
    if (nf == 4) v.w = xp[3];
    xbuf[gid] = v;
}

__global__ void k_zero(int4* __restrict__ p, int n) {
    int idx = blockIdx.x * 256 + threadIdx.x;
    if (idx < n) p[idx] = int4{0, 0, 0, 0};
}

__global__ void k_initout(float* __restrict__ out,
                          const float* __restrict__ lb, const float* __restrict__ qb) {
    int idx = blockIdx.x * 256 + threadIdx.x;      // exactly 772352
    if (idx < BB * NT * 7) {
        int d = idx % 7;
        out[idx] = d < 3 ? lb[d] : qb[d - 3];
    }
}

// Persistent kernel: all 432 steps. 128 blocks, 1/CU, flag-barrier per branch.
__global__ __launch_bounds__(256, 1) void k_persist(
    const unsigned short* __restrict__ wfrag,
    const float* __restrict__ M, const float* __restrict__ bE, const float* __restrict__ bP,
    const float4* __restrict__ xbuf,
    const float* __restrict__ lin_dec_w, const float* __restrict__ quat_dec_w,
    unsigned short* __restrict__ hbuf, float* __restrict__ out, int* __restrict__ flags) {
    extern __shared__ char smem[];
    int4* Bw = (int4*)smem;                         // [2 phase][2 csub][32 kb][64 lane] = 128 KB
    float* h_tile = (float*)(smem + 131072);        // [128][20] f32 = 10240 B

    int tid = threadIdx.x;
    int l = tid & 63;
    int rt = tid >> 6;                              // wave id = row-tile within block
    int blk = blockIdx.x;
    int branch = blk >> 6;
    int rh = (blk >> 5) & 1;
    int cg = blk & 31;
    int nf = 3 + branch;
    int rb_g = rh * 4 + rt;                         // global row-tile for this wave

    // ---- load both weight slices (enc=Whh, pred=Wih) into LDS
#pragma unroll
    for (int p = 0; p < 2; ++p) {
        const int4* src = (const int4*)wfrag + (size_t)(branch * 2 + p) * 131072 + cg * 4096;
        int4* dst = Bw + p * 4096;
        for (int i = tid; i < 4096; i += 256) dst[i] = src[i];
    }

    // ---- loop-invariant per-lane registers
    int c = l & 31;
    bool lo = (c & 16) == 0;
    int jl = c & 15;
    int jcol = cg * 16 + jl;
    float mg[4][4], beEr[4], bePr[4];
#pragma unroll
    for (int g = 0; g < 4; ++g) {
        const float* mm = M + ((size_t)branch * 2048 + g * 512 + jcol) * 4;
#pragma unroll
        for (int kf = 0; kf < 4; ++kf) mg[g][kf] = mm[kf];
        beEr[g] = bE[branch * 2048 + g * 512 + jcol];
        bePr[g] = bP[branch * 2048 + g * 512 + jcol];
    }
    // decoder weights: thread covers rows tid&127, dims d0 and d0+2
    int drow = tid & 127;
    int d0 = tid >> 7;
    const float* dec = branch ? quat_dec_w : lin_dec_w;
    float4 wdr[2][4] = {};
#pragma unroll
    for (int i = 0; i < 2; ++i) {
        int d = d0 + 2 * i;
        if (d < nf) {
            const float4* wp = (const float4*)(dec + d * 512 + cg * 16);
#pragma unroll
            for (int q = 0; q < 4; ++q) wdr[i][q] = wp[q];
        }
    }
    float cst[16];
#pragma unroll
    for (int r = 0; r < 16; ++r) cst[r] = 0.f;

    const int4* Hbase = (const int4*)hbuf;
    int4* HbaseW = (int4*)hbuf;
    int* myflag = flags + blk * 16;

    __syncthreads();   // LDS weights ready

    for (int u = 0; u < NU; ++u) {
        bool enc = u < SS;
        int phase = enc ? 0 : 1;

        // ---- wait for all producers of this branch to finish step u-1
        if (u > 0) {
            if (tid < 64) {
                const int* fp = flags + (branch * 64 + tid) * 16;
                while (__hip_atomic_load(fp, __ATOMIC_RELAXED, __HIP_MEMORY_SCOPE_AGENT) < u)
                    __builtin_amdgcn_s_sleep(1);
            }
            __syncthreads();
            __builtin_amdgcn_fence(__ATOMIC_ACQUIRE, "agent");
        }

        // ---- GEMM: C[32 rows x 64 gatecols] per wave, A from global frag, B from LDS
        f32x16 acc0 = {};
        f32x16 acc1 = {};
        const int4* Ap = Hbase + ((size_t)((u & 1) * 2 + branch) * 8 + rb_g) * 2048 + l;
        const int4* Bp = Bw + phase * 4096 + l;
#pragma unroll
        for (int kb = 0; kb < 32; ++kb) {
            int4 av = Ap[kb * 64];
            int4 b0 = Bp[kb * 64];
            int4 b1 = Bp[2048 + kb * 64];
            acc0 = __builtin_amdgcn_mfma_f32_32x32x16_bf16(*(const bf16x8*)&av, *(const bf16x8*)&b0, acc0, 0, 0, 0);
            acc1 = __builtin_amdgcn_mfma_f32_32x32x16_bf16(*(const bf16x8*)&av, *(const bf16x8*)&b1, acc1, 0, 0, 0);
        }

        // ---- gates in registers (i|f in acc0, g|o in acc1; pair via shfl_xor 16)
        float4 xq[16];
        if (enc) {
            const float4* xb = xbuf + ((size_t)branch * SS + u) * 256;
#pragma unroll
            for (int r = 0; r < 16; ++r) {
                int row_l = rt * 32 + 4 * (l >> 5) + (r & 3) + 8 * (r >> 2);
                xq[r] = xb[rh * 128 + row_l];
            }
        }
#pragma unroll
        for (int r = 0; r < 16; ++r) {
            int row_l = rt * 32 + 4 * (l >> 5) + (r & 3) + 8 * (r >> 2);
            float v0 = acc0[r], v1 = acc1[r];
            float q0 = __shfl_xor(v0, 16);
            float q1 = __shfl_xor(v1, 16);
            float gi = lo ? v0 : q0;
            float gf = lo ? q0 : v0;
            float gg = lo ? v1 : q1;
            float go = lo ? q1 : v1;
            float hv;
            if (enc) {
                float4 xv = xq[r];
                gi += beEr[0] + xv.x * mg[0][0] + xv.y * mg[0][1] + xv.z * mg[0][2] + xv.w * mg[0][3];
                gf += beEr[1] + xv.x * mg[1][0] + xv.y * mg[1][1] + xv.z * mg[1][2] + xv.w * mg[1][3];
                gg += beEr[2] + xv.x * mg[2][0] + xv.y * mg[2][1] + xv.z * mg[2][2] + xv.w * mg[2][3];
                go += beEr[3] + xv.x * mg[3][0] + xv.y * mg[3][1] + xv.z * mg[3][2] + xv.w * mg[3][3];
                float cn = sigm(gf) * cst[r] + sigm(gi) * tanh_(gg);
                cst[r] = cn;
                hv = sigm(go) * tanh_(cn);
            } else {
                gi += bePr[0];
                gg += bePr[2];
                go += bePr[3];
                float cn = sigm(gi) * tanh_(gg);   // zero initial state in pred phase
                hv = sigm(go) * tanh_(cn);
            }
            if (lo) h_tile[row_l * 20 + jl] = hv;
        }
        __syncthreads();

        // ---- store h (bf16 A-fragment order) for next step
        {
            int rbl = tid >> 6;
            int fl = tid & 63;
            int row_l = rbl * 32 + (fl & 31);
            int jh = (fl >> 5) * 8;
            const float* hp = h_tile + row_l * 20 + jh;
            float4 f0 = ((const float4*)hp)[0];
            float4 f1 = ((const float4*)hp)[1];
            unsigned short us[8];
            us[0] = f2bf(f0.x); us[1] = f2bf(f0.y); us[2] = f2bf(f0.z); us[3] = f2bf(f0.w);
            us[4] = f2bf(f1.x); us[5] = f2bf(f1.y); us[6] = f2bf(f1.z); us[7] = f2bf(f1.w);
            int4 v;
            v.x = us[0] | (us[1] << 16); v.y = us[2] | (us[3] << 16);
            v.z = us[4] | (us[5] << 16); v.w = us[6] | (us[7] << 16);
            HbaseW[(((size_t)(((u + 1) & 1) * 2 + branch) * 8 + (rh * 4 + rbl)) * 32 + cg) * 64 + fl] = v;
        }

        // ---- fused decoder partial (16 h-cols), atomic accumulate
        if (u >= 1) {
            const float* hrow = h_tile + drow * 20;
            float4 h0 = ((const float4*)hrow)[0];
            float4 h1 = ((const float4*)hrow)[1];
            float4 h2 = ((const float4*)hrow)[2];
            float4 h3 = ((const float4*)hrow)[3];
            int bg = rh * 128 + drow;
#pragma unroll
            for (int i = 0; i < 2; ++i) {
                int d = d0 + 2 * i;
                if (d < nf) {
                    float s = h0.x * wdr[i][0].x + h0.y * wdr[i][0].y + h0.z * wdr[i][0].z + h0.w * wdr[i][0].w
                            + h1.x * wdr[i][1].x + h1.y * wdr[i][1].y + h1.z * wdr[i][1].z + h1.w * wdr[i][1].w
                            + h2.x * wdr[i][2].x + h2.y * wdr[i][2].y + h2.z * wdr[i][2].z + h2.w * wdr[i][2].w
                            + h3.x * wdr[i][3].x + h3.y * wdr[i][3].y + h3.z * wdr[i][3].z + h3.w * wdr[i][3].w;
                    unsafeAtomicAdd(out + ((size_t)bg * NT + (u - 1)) * 7 + branch * 3 + d, s);
                }
            }
        }
        __syncthreads();   // h_tile + stores done block-wide

        // ---- publish step completion (release pushes XCD L2 to LLC)
        if (tid == 0)
            __hip_atomic_store(myflag, u + 1, __ATOMIC_RELEASE, __HIP_MEMORY_SCOPE_AGENT);
    }
}

extern "C" void kernel_launch(void* const* d_in, const int* in_sizes, int n_in,
                              void* d_out, int out_size, void* d_ws, size_t ws_size,
                              hipStream_t stream) {
    const float* x          = (const float*)d_in[0];
    const float* lin_enc_w  = (const float*)d_in[1];
    const float* lin_enc_b  = (const float*)d_in[2];
    const float* quat_enc_w = (const float*)d_in[3];
    const float* quat_enc_b = (const float*)d_in[4];
    const float* lin_wih    = (const float*)d_in[5];
    const float* lin_whh    = (const float*)d_in[6];
    const float* lin_bih    = (const float*)d_in[7];
    const float* lin_bhh    = (const float*)d_in[8];
    const float* quat_wih   = (const float*)d_in[9];
    const float* quat_whh   = (const float*)d_in[10];
    const float* quat_bih   = (const float*)d_in[11];
    const float* quat_bhh   = (const float*)d_in[12];
    const float* lin_dec_w  = (const float*)d_in[13];
    const float* lin_dec_b  = (const float*)d_in[14];
    const float* quat_dec_w = (const float*)d_in[15];
    const float* quat_dec_b = (const float*)d_in[16];
    float* out = (float*)d_out;
    char* ws = (char*)d_ws;

    unsigned short* wfrag = (unsigned short*)(ws + 0);
    unsigned short* hbuf  = (unsigned short*)(ws + 8388608ull);
    int* flags            = (int*)(ws + 9437184ull);
    float4* xbuf          = (float4*)(ws + 9445376ull);
    float* M              = (float*)(ws + 12197888ull);
    float* bE             = (float*)(ws + 12263424ull);
    float* bP             = (float*)(ws + 12279808ull);

    static const int kDynLds = 131072 + 128 * 20 * 4;   // 141312
    hipFuncSetAttribute((const void*)k_persist,
                        hipFuncAttributeMaxDynamicSharedMemorySize, kDynLds);

    k_wfrag<<<2048, 256, 0, stream>>>(lin_whh, lin_wih, quat_whh, quat_wih, wfrag);
    k_mbias<<<16, 256, 0, stream>>>(lin_wih, quat_wih, lin_enc_w, quat_enc_w,
                                    lin_enc_b, quat_enc_b, lin_bih, lin_bhh,
                                    quat_bih, quat_bhh, M, bE, bP);
    k_xprep<<<672, 256, 0, stream>>>(x, xbuf);
    // zero hbuf (1 MB) + flags (8 KB) in one pass: 66048 int4
    k_zero<<<258, 256, 0, stream>>>((int4*)(ws + 8388608ull), 66048);
    k_initout<<<3017, 256, 0, stream>>>(out, lin_dec_b, quat_dec_b);

    k_persist<<<NBLK, 256, kDynLds, stream>>>(wfrag, M, bE, bP, xbuf,
                                              lin_dec_w, quat_dec_w,
                                              hbuf, out, flags);
}

// Round 5
// 7394.249 us; speedup vs baseline: 1.3889x; 1.3889x over previous
//
#include <hip/hip_runtime.h>

#define BB 256
#define SS 336
#define NT 431   // output time steps
#define NU 432   // total cell steps
#define NBLK 128 // 2 branch * 2 rowhalf * 32 colgroup

typedef __attribute__((ext_vector_type(8))) short bf16x8;
typedef __attribute__((ext_vector_type(16))) float f32x16;

// ---------------- ws layout (bytes) ----------------
// wfrag @ 0        : 8388608  (4 mats x [cg32][csub2][kb32][lane64] int4)
// hbuf  @ 8388608  : 1048576  ([par2][br2][rb8][kb32][lane64] int4)
// cnt   @ 9437184  : 27648    ([16 chains][432 steps] int)
// xbuf  @ 9469952  : 2752512  ([br2][336][256] float4)
// M     @ 12222464 : 65536    ([2][2048][4] f32)
// bE    @ 12288000 : 16384
// bP    @ 12304384 : 16384

__device__ inline unsigned short f2bf(float f) {
    unsigned int u = __float_as_uint(f);
    unsigned int r = (u + 0x7fffu + ((u >> 16) & 1u)) >> 16;
    return (unsigned short)r;
}
__device__ inline float sigm(float x) { return 1.f / (1.f + __expf(-x)); }
__device__ inline float tanh_(float x) { return 2.f / (1.f + __expf(-2.f * x)) - 1.f; }

// f32 [2048][512] -> bf16 MFMA B-fragment order [mat][cg][csub][kb][lane] int4
__global__ void k_wfrag(const float* __restrict__ w0, const float* __restrict__ w1,
                        const float* __restrict__ w2, const float* __restrict__ w3,
                        unsigned short* __restrict__ wfrag) {
    int idx = blockIdx.x * 256 + threadIdx.x;      // 0 .. 524287
    int mat = idx >> 17;
    int t = idx & 131071;
    int lane = t & 63;
    int kb = (t >> 6) & 31;
    int csub = (t >> 11) & 1;
    int cg = t >> 12;
    const float* W = mat == 0 ? w0 : (mat == 1 ? w1 : (mat == 2 ? w2 : w3));
    int n_local = csub * 32 + (lane & 31);
    int n = (n_local >> 4) * 512 + cg * 16 + (n_local & 15);
    int k0 = kb * 16 + (lane >> 5) * 8;
    const float* src = W + n * 512 + k0;
    unsigned short us[8];
#pragma unroll
    for (int j = 0; j < 8; ++j) us[j] = f2bf(src[j]);
    int4 v;
    v.x = (int)((unsigned int)us[0] | ((unsigned int)us[1] << 16));
    v.y = (int)((unsigned int)us[2] | ((unsigned int)us[3] << 16));
    v.z = (int)((unsigned int)us[4] | ((unsigned int)us[5] << 16));
    v.w = (int)((unsigned int)us[6] | ((unsigned int)us[7] << 16));
    ((int4*)wfrag)[idx] = v;
}

__global__ void k_mbias(const float* __restrict__ lin_wih, const float* __restrict__ quat_wih,
                        const float* __restrict__ lin_enc_w, const float* __restrict__ quat_enc_w,
                        const float* __restrict__ lin_enc_b, const float* __restrict__ quat_enc_b,
                        const float* __restrict__ lin_bih, const float* __restrict__ lin_bhh,
                        const float* __restrict__ quat_bih, const float* __restrict__ quat_bhh,
                        float* __restrict__ M, float* __restrict__ bE, float* __restrict__ bP) {
    int gid = blockIdx.x * 256 + threadIdx.x;      // 0..4095
    int branch = gid >> 11;
    int n = gid & 2047;
    int nf = 3 + branch;
    const float* Wih = branch ? quat_wih : lin_wih;
    const float* We  = branch ? quat_enc_w : lin_enc_w;
    const float* be  = branch ? quat_enc_b : lin_enc_b;
    const float* bih = branch ? quat_bih : lin_bih;
    const float* bhh = branch ? quat_bhh : lin_bhh;
    float m[4] = {0.f, 0.f, 0.f, 0.f};
    float bs = 0.f;
    for (int j = 0; j < 512; ++j) {
        float w = Wih[n * 512 + j];
#pragma unroll
        for (int kf = 0; kf < 4; ++kf)
            if (kf < nf) m[kf] += w * We[j * nf + kf];
        bs += w * be[j];
    }
    float* Mp = M + (branch * 2048 + n) * 4;
#pragma unroll
    for (int kf = 0; kf < 4; ++kf) Mp[kf] = m[kf];
    bE[branch * 2048 + n] = bs + bih[n] + bhh[n];
    bP[branch * 2048 + n] = bih[n] + bhh[n];
}

// xbuf[branch][u][b] = float4 of x[b,u, branch*3 .. +nf)
__global__ void k_xprep(const float* __restrict__ x, float4* __restrict__ xbuf) {
    int gid = blockIdx.x * 256 + threadIdx.x;      // 0..172031
    int branch = gid / 86016;
    int rem = gid - branch * 86016;
    int u = rem >> 8;
    int b = rem & 255;
    int nf = 3 + branch;
    const float* xp = x + (b * SS + u) * 7 + branch * 3;
    float4 v = {0.f, 0.f, 0.f, 0.f};
    v.x = xp[0]; v.y = xp[1]; v.z = xp[2];
    if (nf == 4) v.w = xp[3];
    xbuf[gid] = v;
}

__global__ void k_zero(int4* __restrict__ p, int n) {
    int idx = blockIdx.x * 256 + threadIdx.x;
    if (idx < n) p[idx] = int4{0, 0, 0, 0};
}

__global__ void k_initout(float* __restrict__ out,
                          const float* __restrict__ lb, const float* __restrict__ qb) {
    int idx = blockIdx.x * 256 + threadIdx.x;      // exactly 772352
    if (idx < BB * NT * 7) {
        int d = idx % 7;
        out[idx] = d < 3 ? lb[d] : qb[d - 3];
    }
}

// Persistent kernel. 128 blocks, 1/CU. 16 independent chains = (branch,rh,rt),
// 32 producer waves (cg) per chain. h published via atomicExch u64 RMWs
// (device-coherent point; vmcnt(0) retirement => globally visible), flag via
// atomicAdd RMW, poll via lane-0 fetch_add(0) RMW. Bulk A reads are relaxed
// agent-scope atomic u64 loads. No fences, no in-loop __syncthreads.
__global__ __launch_bounds__(256, 1) void k_persist(
    const unsigned short* __restrict__ wfrag,
    const float* __restrict__ M, const float* __restrict__ bE, const float* __restrict__ bP,
    const float4* __restrict__ xbuf,
    const float* __restrict__ lin_dec_w, const float* __restrict__ quat_dec_w,
    unsigned long long* __restrict__ hbuf, float* __restrict__ out, int* __restrict__ cnt) {
    extern __shared__ char smem[];
    int4* Bw = (int4*)smem;                         // [2 phase][2 csub][32 kb][64 lane] = 128 KB
    float* h_tile = (float*)(smem + 131072);        // [128][20] f32

    int tid = threadIdx.x;
    int l = tid & 63;
    int rt = tid >> 6;                              // wave id = row-tile within block
    int blk = blockIdx.x;
    int branch = blk >> 6;
    int rh = (blk >> 5) & 1;
    int cg = blk & 31;
    int nf = 3 + branch;
    int rb_g = rh * 4 + rt;
    int chain = branch * 8 + rh * 4 + rt;

    // ---- load both weight slices (enc=Whh, pred=Wih) into LDS
#pragma unroll
    for (int p = 0; p < 2; ++p) {
        const int4* src = (const int4*)wfrag + (size_t)(branch * 2 + p) * 131072 + cg * 4096;
        int4* dst = Bw + p * 4096;
        for (int i = tid; i < 4096; i += 256) dst[i] = src[i];
    }

    // ---- loop-invariant per-lane registers
    int c = l & 31;
    bool lo = (c & 16) == 0;
    int jl = c & 15;
    int jcol = cg * 16 + jl;
    float mg[4][4], beEr[4], bePr[4];
#pragma unroll
    for (int g = 0; g < 4; ++g) {
        const float* mm = M + ((size_t)branch * 2048 + g * 512 + jcol) * 4;
#pragma unroll
        for (int kf = 0; kf < 4; ++kf) mg[g][kf] = mm[kf];
        beEr[g] = bE[branch * 2048 + g * 512 + jcol];
        bePr[g] = bP[branch * 2048 + g * 512 + jcol];
    }
    // decoder weights: lane covers row (l&31) of its wave, dims d = (l>>5) + 2i
    const float* dec = branch ? quat_dec_w : lin_dec_w;
    float4 wdr[2][4] = {};
#pragma unroll
    for (int i = 0; i < 2; ++i) {
        int d = (l >> 5) + 2 * i;
        if (d < nf) {
            const float4* wp = (const float4*)(dec + d * 512 + cg * 16);
#pragma unroll
            for (int q = 0; q < 4; ++q) wdr[i][q] = wp[q];
        }
    }
    float cst[16];
#pragma unroll
    for (int r = 0; r < 16; ++r) cst[r] = 0.f;

    float* my_rows = h_tile + rt * 32 * 20;         // wave-private 32 rows
    __syncthreads();                                // LDS weights ready (only barrier)

    for (int u = 0; u < NU; ++u) {
        bool enc = u < SS;
        int phase = enc ? 0 : 1;

        // ---- wait for the 32 producers of this chain to finish step u-1
        if (u > 0) {
            int* cp = cnt + chain * NU + (u - 1);
            if (l == 0) {
                while (__hip_atomic_fetch_add(cp, 0, __ATOMIC_RELAXED, __HIP_MEMORY_SCOPE_AGENT) < 32)
                    __builtin_amdgcn_s_sleep(1);
            }
            asm volatile("" ::: "memory");   // pin program order: no A-load hoist above poll
        }

        // ---- x for this step
        float4 xq[16];
        if (enc) {
            const float4* xb = xbuf + ((size_t)branch * SS + u) * 256 + rh * 128 + rt * 32;
#pragma unroll
            for (int r = 0; r < 16; ++r) {
                int row_l = 4 * (l >> 5) + (r & 3) + 8 * (r >> 2);
                xq[r] = xb[row_l];
            }
        }

        // ---- GEMM: C[32 rows x 64 gatecols]; A via agent-coherent u64 loads, B from LDS
        f32x16 acc0 = {};
        f32x16 acc1 = {};
        const unsigned long long* Ap =
            hbuf + (((size_t)((u & 1) * 2 + branch) * 8 + rb_g) * 2048 + l) * 2;
        const int4* Bp = Bw + phase * 4096 + l;
#pragma unroll
        for (int kb = 0; kb < 32; ++kb) {
            union { unsigned long long u64[2]; bf16x8 v; } a;
            a.u64[0] = __hip_atomic_load(Ap + kb * 128 + 0, __ATOMIC_RELAXED, __HIP_MEMORY_SCOPE_AGENT);
            a.u64[1] = __hip_atomic_load(Ap + kb * 128 + 1, __ATOMIC_RELAXED, __HIP_MEMORY_SCOPE_AGENT);
            int4 b0 = Bp[kb * 64];
            int4 b1 = Bp[2048 + kb * 64];
            acc0 = __builtin_amdgcn_mfma_f32_32x32x16_bf16(a.v, *(const bf16x8*)&b0, acc0, 0, 0, 0);
            acc1 = __builtin_amdgcn_mfma_f32_32x32x16_bf16(a.v, *(const bf16x8*)&b1, acc1, 0, 0, 0);
        }

        // ---- gates in registers (i|f in acc0, g|o in acc1; pair via shfl_xor 16)
#pragma unroll
        for (int r = 0; r < 16; ++r) {
            int row_l = 4 * (l >> 5) + (r & 3) + 8 * (r >> 2);   // 0..31 within wave
            float v0 = acc0[r], v1 = acc1[r];
            float q0 = __shfl_xor(v0, 16);
            float q1 = __shfl_xor(v1, 16);
            float gi = lo ? v0 : q0;
            float gf = lo ? q0 : v0;
            float gg = lo ? v1 : q1;
            float go = lo ? q1 : v1;
            float hv;
            if (enc) {
                float4 xv = xq[r];
                gi += beEr[0] + xv.x * mg[0][0] + xv.y * mg[0][1] + xv.z * mg[0][2] + xv.w * mg[0][3];
                gf += beEr[1] + xv.x * mg[1][0] + xv.y * mg[1][1] + xv.z * mg[1][2] + xv.w * mg[1][3];
                gg += beEr[2] + xv.x * mg[2][0] + xv.y * mg[2][1] + xv.z * mg[2][2] + xv.w * mg[2][3];
                go += beEr[3] + xv.x * mg[3][0] + xv.y * mg[3][1] + xv.z * mg[3][2] + xv.w * mg[3][3];
                float cn = sigm(gf) * cst[r] + sigm(gi) * tanh_(gg);
                cst[r] = cn;
                hv = sigm(go) * tanh_(cn);
            } else {
                gi += bePr[0];
                gg += bePr[2];
                go += bePr[3];
                float cn = sigm(gi) * tanh_(gg);   // zero initial state in pred phase
                hv = sigm(go) * tanh_(cn);
            }
            if (lo) my_rows[row_l * 20 + jl] = hv;   // wave-private LDS rows
        }

        // ---- pack + publish h slice (32 rows x 16 cols) via atomicExch RMWs
        // NOTE: pack through unsigned temporaries — (us<<16) as int sign-extends
        // into the u64 high word and fabricates bf16 NaNs (rounds 3/4 bug).
        {
            const float* hp = my_rows + (l & 31) * 20 + (l >> 5) * 8;
            float4 f0 = ((const float4*)hp)[0];
            float4 f1 = ((const float4*)hp)[1];
            unsigned int w0 = (unsigned int)f2bf(f0.x) | ((unsigned int)f2bf(f0.y) << 16);
            unsigned int w1 = (unsigned int)f2bf(f0.z) | ((unsigned int)f2bf(f0.w) << 16);
            unsigned int w2 = (unsigned int)f2bf(f1.x) | ((unsigned int)f2bf(f1.y) << 16);
            unsigned int w3 = (unsigned int)f2bf(f1.z) | ((unsigned int)f2bf(f1.w) << 16);
            unsigned long long s0 = (unsigned long long)w0 | ((unsigned long long)w1 << 32);
            unsigned long long s1 = (unsigned long long)w2 | ((unsigned long long)w3 << 32);
            size_t widx = ((((size_t)(((u + 1) & 1) * 2 + branch) * 8 + rb_g) * 32 + cg) * 64 + l) * 2;
            atomicExch(hbuf + widx + 0, s0);
            atomicExch(hbuf + widx + 1, s1);
        }
        asm volatile("s_waitcnt vmcnt(0)" ::: "memory");   // RMWs acked at coherent point
        if (l == 0)
            atomicAdd(cnt + chain * NU + u, 1);

        // ---- fused decoder (after publish; doesn't block consumers)
        if (u >= 1) {
            const float* hrow = my_rows + (l & 31) * 20;
            float4 h0 = ((const float4*)hrow)[0];
            float4 h1 = ((const float4*)hrow)[1];
            float4 h2 = ((const float4*)hrow)[2];
            float4 h3 = ((const float4*)hrow)[3];
            int bg = rh * 128 + rt * 32 + (l & 31);
#pragma unroll
            for (int i = 0; i < 2; ++i) {
                int d = (l >> 5) + 2 * i;
                if (d < nf) {
                    float s = h0.x * wdr[i][0].x + h0.y * wdr[i][0].y + h0.z * wdr[i][0].z + h0.w * wdr[i][0].w
                            + h1.x * wdr[i][1].x + h1.y * wdr[i][1].y + h1.z * wdr[i][1].z + h1.w * wdr[i][1].w
                            + h2.x * wdr[i][2].x + h2.y * wdr[i][2].y + h2.z * wdr[i][2].z + h2.w * wdr[i][2].w
                            + h3.x * wdr[i][3].x + h3.y * wdr[i][3].y + h3.z * wdr[i][3].z + h3.w * wdr[i][3].w;
                    unsafeAtomicAdd(out + ((size_t)bg * NT + (u - 1)) * 7 + branch * 3 + d, s);
                }
            }
        }
    }
}

extern "C" void kernel_launch(void* const* d_in, const int* in_sizes, int n_in,
                              void* d_out, int out_size, void* d_ws, size_t ws_size,
                              hipStream_t stream) {
    const float* x          = (const float*)d_in[0];
    const float* lin_enc_w  = (const float*)d_in[1];
    const float* lin_enc_b  = (const float*)d_in[2];
    const float* quat_enc_w = (const float*)d_in[3];
    const float* quat_enc_b = (const float*)d_in[4];
    const float* lin_wih    = (const float*)d_in[5];
    const float* lin_whh    = (const float*)d_in[6];
    const float* lin_bih    = (const float*)d_in[7];
    const float* lin_bhh    = (const float*)d_in[8];
    const float* quat_wih   = (const float*)d_in[9];
    const float* quat_whh   = (const float*)d_in[10];
    const float* quat_bih   = (const float*)d_in[11];
    const float* quat_bhh   = (const float*)d_in[12];
    const float* lin_dec_w  = (const float*)d_in[13];
    const float* lin_dec_b  = (const float*)d_in[14];
    const float* quat_dec_w = (const float*)d_in[15];
    const float* quat_dec_b = (const float*)d_in[16];
    float* out = (float*)d_out;
    char* ws = (char*)d_ws;

    unsigned short* wfrag     = (unsigned short*)(ws + 0);
    unsigned long long* hbuf  = (unsigned long long*)(ws + 8388608ull);
    int* cnt                  = (int*)(ws + 9437184ull);
    float4* xbuf              = (float4*)(ws + 9469952ull);
    float* M                  = (float*)(ws + 12222464ull);
    float* bE                 = (float*)(ws + 12288000ull);
    float* bP                 = (float*)(ws + 12304384ull);

    static const int kDynLds = 131072 + 128 * 20 * 4;   // 141312
    hipFuncSetAttribute((const void*)k_persist,
                        hipFuncAttributeMaxDynamicSharedMemorySize, kDynLds);

    k_wfrag<<<2048, 256, 0, stream>>>(lin_whh, lin_wih, quat_whh, quat_wih, wfrag);
    k_mbias<<<16, 256, 0, stream>>>(lin_wih, quat_wih, lin_enc_w, quat_enc_w,
                                    lin_enc_b, quat_enc_b, lin_bih, lin_bhh,
                                    quat_bih, quat_bhh, M, bE, bP);
    k_xprep<<<672, 256, 0, stream>>>(x, xbuf);
    // zero hbuf (65536 int4) + cnt (1728 int4) contiguously
    k_zero<<<263, 256, 0, stream>>>((int4*)(ws + 8388608ull), 67264);
    k_initout<<<3017, 256, 0, stream>>>(out, lin_dec_b, quat_dec_b);

    k_persist<<<NBLK, 256, kDynLds, stream>>>(wfrag, M, bE, bP, xbuf,
                                              lin_dec_w, quat_dec_w,
                                              hbuf, out, cnt);
}

// Round 6
// 7111.346 us; speedup vs baseline: 1.4441x; 1.0398x over previous
//
#include <hip/hip_runtime.h>

#define BB 256
#define SS 336
#define NT 431   // output time steps
#define NU 432   // total cell steps
#define NBLK 128 // 2 branch * 2 rowhalf * 32 colgroup

typedef __attribute__((ext_vector_type(8))) short bf16x8;
typedef __attribute__((ext_vector_type(16))) float f32x16;

// ---------------- ws layout (bytes) ----------------
// wfrag @ 0        : 8388608  (4 mats x [cg32][csub2][kb32][lane64] int4)
// hbuf  @ 8388608  : 1048576  ([par2][br2][rb8][kb32][lane64] int4)
// flags @ 9437184  : 8192     ([16 chains][32 cg] int, zero-padded)
// xbuf  @ 9469952  : 2752512  ([br2][336][256] float4)
// M     @ 12222464 : 65536    ([2][2048][4] f32)
// bE    @ 12288000 : 16384
// bP    @ 12304384 : 16384

__device__ inline unsigned short f2bf(float f) {
    unsigned int u = __float_as_uint(f);
    unsigned int r = (u + 0x7fffu + ((u >> 16) & 1u)) >> 16;
    return (unsigned short)r;
}
__device__ inline float sigm(float x) { return 1.f / (1.f + __expf(-x)); }
__device__ inline float tanh_(float x) { return 2.f / (1.f + __expf(-2.f * x)) - 1.f; }

// f32 [2048][512] -> bf16 MFMA B-fragment order [mat][cg][csub][kb][lane] int4
__global__ void k_wfrag(const float* __restrict__ w0, const float* __restrict__ w1,
                        const float* __restrict__ w2, const float* __restrict__ w3,
                        unsigned short* __restrict__ wfrag) {
    int idx = blockIdx.x * 256 + threadIdx.x;      // 0 .. 524287
    int mat = idx >> 17;
    int t = idx & 131071;
    int lane = t & 63;
    int kb = (t >> 6) & 31;
    int csub = (t >> 11) & 1;
    int cg = t >> 12;
    const float* W = mat == 0 ? w0 : (mat == 1 ? w1 : (mat == 2 ? w2 : w3));
    int n_local = csub * 32 + (lane & 31);
    int n = (n_local >> 4) * 512 + cg * 16 + (n_local & 15);
    int k0 = kb * 16 + (lane >> 5) * 8;
    const float* src = W + n * 512 + k0;
    unsigned short us[8];
#pragma unroll
    for (int j = 0; j < 8; ++j) us[j] = f2bf(src[j]);
    int4 v;
    v.x = (int)((unsigned int)us[0] | ((unsigned int)us[1] << 16));
    v.y = (int)((unsigned int)us[2] | ((unsigned int)us[3] << 16));
    v.z = (int)((unsigned int)us[4] | ((unsigned int)us[5] << 16));
    v.w = (int)((unsigned int)us[6] | ((unsigned int)us[7] << 16));
    ((int4*)wfrag)[idx] = v;
}

__global__ void k_mbias(const float* __restrict__ lin_wih, const float* __restrict__ quat_wih,
                        const float* __restrict__ lin_enc_w, const float* __restrict__ quat_enc_w,
                        const float* __restrict__ lin_enc_b, const float* __restrict__ quat_enc_b,
                        const float* __restrict__ lin_bih, const float* __restrict__ lin_bhh,
                        const float* __restrict__ quat_bih, const float* __restrict__ quat_bhh,
                        float* __restrict__ M, float* __restrict__ bE, float* __restrict__ bP) {
    int gid = blockIdx.x * 256 + threadIdx.x;      // 0..4095
    int branch = gid >> 11;
    int n = gid & 2047;
    int nf = 3 + branch;
    const float* Wih = branch ? quat_wih : lin_wih;
    const float* We  = branch ? quat_enc_w : lin_enc_w;
    const float* be  = branch ? quat_enc_b : lin_enc_b;
    const float* bih = branch ? quat_bih : lin_bih;
    const float* bhh = branch ? quat_bhh : lin_bhh;
    float m[4] = {0.f, 0.f, 0.f, 0.f};
    float bs = 0.f;
    for (int j = 0; j < 512; ++j) {
        float w = Wih[n * 512 + j];
#pragma unroll
        for (int kf = 0; kf < 4; ++kf)
            if (kf < nf) m[kf] += w * We[j * nf + kf];
        bs += w * be[j];
    }
    float* Mp = M + (branch * 2048 + n) * 4;
#pragma unroll
    for (int kf = 0; kf < 4; ++kf) Mp[kf] = m[kf];
    bE[branch * 2048 + n] = bs + bih[n] + bhh[n];
    bP[branch * 2048 + n] = bih[n] + bhh[n];
}

// xbuf[branch][u][b] = float4 of x[b,u, branch*3 .. +nf)
__global__ void k_xprep(const float* __restrict__ x, float4* __restrict__ xbuf) {
    int gid = blockIdx.x * 256 + threadIdx.x;      // 0..172031
    int branch = gid / 86016;
    int rem = gid - branch * 86016;
    int u = rem >> 8;
    int b = rem & 255;
    int nf = 3 + branch;
    const float* xp = x + (b * SS + u) * 7 + branch * 3;
    float4 v = {0.f, 0.f, 0.f, 0.f};
    v.x = xp[0]; v.y = xp[1]; v.z = xp[2];
    if (nf == 4) v.w = xp[3];
    xbuf[gid] = v;
}

__global__ void k_zero(int4* __restrict__ p, int n) {
    int idx = blockIdx.x * 256 + threadIdx.x;
    if (idx < n) p[idx] = int4{0, 0, 0, 0};
}

__global__ void k_initout(float* __restrict__ out,
                          const float* __restrict__ lb, const float* __restrict__ qb) {
    int idx = blockIdx.x * 256 + threadIdx.x;      // exactly 772352
    if (idx < BB * NT * 7) {
        int d = idx % 7;
        out[idx] = d < 3 ? lb[d] : qb[d - 3];
    }
}

// Persistent kernel. 128 blocks, 1/CU. 16 independent chains = (branch,rh,rt),
// 32 producer waves (cg) per chain. ALL sync is contention-free:
//  - h data: SYSTEM-scope relaxed atomic u64 stores (plain sc0 sc1 write-through
//    to LLC, no RMW), drained by vmcnt(0)
//  - flag: one plain sc0 sc1 store per wave into flags[chain][cg]
//  - poll: lanes 0..31 read the 32 flags with one coalesced sc0 sc1 load,
//    __all(f>=u) — reads don't serialize at the LLC banks
//  - A: SYSTEM-scope relaxed atomic u64 loads (coherent LLC reads)
// No fences, no RMWs on hot lines, no in-loop __syncthreads.
__global__ __launch_bounds__(256, 1) void k_persist(
    const unsigned short* __restrict__ wfrag,
    const float* __restrict__ M, const float* __restrict__ bE, const float* __restrict__ bP,
    const float4* __restrict__ xbuf,
    const float* __restrict__ lin_dec_w, const float* __restrict__ quat_dec_w,
    unsigned long long* __restrict__ hbuf, float* __restrict__ out, int* __restrict__ flags) {
    extern __shared__ char smem[];
    int4* Bw = (int4*)smem;                         // [2 phase][2 csub][32 kb][64 lane] = 128 KB
    float* h_tile = (float*)(smem + 131072);        // [128][20] f32

    int tid = threadIdx.x;
    int l = tid & 63;
    int rt = tid >> 6;                              // wave id = row-tile within block
    int blk = blockIdx.x;
    int branch = blk >> 6;
    int rh = (blk >> 5) & 1;
    int cg = blk & 31;
    int nf = 3 + branch;
    int rb_g = rh * 4 + rt;
    int chain = branch * 8 + rh * 4 + rt;

    // ---- load both weight slices (enc=Whh, pred=Wih) into LDS
#pragma unroll
    for (int p = 0; p < 2; ++p) {
        const int4* src = (const int4*)wfrag + (size_t)(branch * 2 + p) * 131072 + cg * 4096;
        int4* dst = Bw + p * 4096;
        for (int i = tid; i < 4096; i += 256) dst[i] = src[i];
    }

    // ---- loop-invariant per-lane registers
    int c = l & 31;
    bool lo = (c & 16) == 0;
    int jl = c & 15;
    int jcol = cg * 16 + jl;
    float mg[4][4], beEr[4], bePr[4];
#pragma unroll
    for (int g = 0; g < 4; ++g) {
        const float* mm = M + ((size_t)branch * 2048 + g * 512 + jcol) * 4;
#pragma unroll
        for (int kf = 0; kf < 4; ++kf) mg[g][kf] = mm[kf];
        beEr[g] = bE[branch * 2048 + g * 512 + jcol];
        bePr[g] = bP[branch * 2048 + g * 512 + jcol];
    }
    // decoder weights: lane covers row (l&31) of its wave, dims d = (l>>5) + 2i
    const float* dec = branch ? quat_dec_w : lin_dec_w;
    float4 wdr[2][4] = {};
#pragma unroll
    for (int i = 0; i < 2; ++i) {
        int d = (l >> 5) + 2 * i;
        if (d < nf) {
            const float4* wp = (const float4*)(dec + d * 512 + cg * 16);
#pragma unroll
            for (int q = 0; q < 4; ++q) wdr[i][q] = wp[q];
        }
    }
    float cst[16];
#pragma unroll
    for (int r = 0; r < 16; ++r) cst[r] = 0.f;

    float* my_rows = h_tile + rt * 32 * 20;         // wave-private 32 rows
    const int* myflags = flags + chain * 32;
    __syncthreads();                                // LDS weights ready (only barrier)

    for (int u = 0; u < NU; ++u) {
        bool enc = u < SS;
        int phase = enc ? 0 : 1;

        // ---- x for this step (independent of h; overlap with the wait)
        float4 xq[16];
        if (enc) {
            const float4* xb = xbuf + ((size_t)branch * SS + u) * 256 + rh * 128 + rt * 32;
#pragma unroll
            for (int r = 0; r < 16; ++r) {
                int row_l = 4 * (l >> 5) + (r & 3) + 8 * (r >> 2);
                xq[r] = xb[row_l];
            }
        }

        // ---- wait for the 32 producers of this chain to finish step u-1
        // (parallel flag read: one coalesced LLC load per iteration, no RMWs)
        if (u > 0) {
            bool ok;
            do {
                int f = 0x7fffffff;
                if (l < 32)
                    f = __hip_atomic_load(myflags + l, __ATOMIC_RELAXED, __HIP_MEMORY_SCOPE_SYSTEM);
                ok = __all(f >= u);
                if (!ok) __builtin_amdgcn_s_sleep(1);
            } while (!ok);
            asm volatile("" ::: "memory");   // no A-load hoist above the poll
        }

        // ---- GEMM: C[32 rows x 64 gatecols]; A via coherent LLC loads, B from LDS
        f32x16 acc0 = {};
        f32x16 acc1 = {};
        const unsigned long long* Ap =
            hbuf + (((size_t)((u & 1) * 2 + branch) * 8 + rb_g) * 2048 + l) * 2;
        const int4* Bp = Bw + phase * 4096 + l;
#pragma unroll
        for (int kb = 0; kb < 32; ++kb) {
            union { unsigned long long u64[2]; bf16x8 v; } a;
            a.u64[0] = __hip_atomic_load(Ap + kb * 128 + 0, __ATOMIC_RELAXED, __HIP_MEMORY_SCOPE_SYSTEM);
            a.u64[1] = __hip_atomic_load(Ap + kb * 128 + 1, __ATOMIC_RELAXED, __HIP_MEMORY_SCOPE_SYSTEM);
            int4 b0 = Bp[kb * 64];
            int4 b1 = Bp[2048 + kb * 64];
            acc0 = __builtin_amdgcn_mfma_f32_32x32x16_bf16(a.v, *(const bf16x8*)&b0, acc0, 0, 0, 0);
            acc1 = __builtin_amdgcn_mfma_f32_32x32x16_bf16(a.v, *(const bf16x8*)&b1, acc1, 0, 0, 0);
        }

        // ---- gates in registers (i|f in acc0, g|o in acc1; pair via shfl_xor 16)
#pragma unroll
        for (int r = 0; r < 16; ++r) {
            int row_l = 4 * (l >> 5) + (r & 3) + 8 * (r >> 2);   // 0..31 within wave
            float v0 = acc0[r], v1 = acc1[r];
            float q0 = __shfl_xor(v0, 16);
            float q1 = __shfl_xor(v1, 16);
            float gi = lo ? v0 : q0;
            float gf = lo ? q0 : v0;
            float gg = lo ? v1 : q1;
            float go = lo ? q1 : v1;
            float hv;
            if (enc) {
                float4 xv = xq[r];
                gi += beEr[0] + xv.x * mg[0][0] + xv.y * mg[0][1] + xv.z * mg[0][2] + xv.w * mg[0][3];
                gf += beEr[1] + xv.x * mg[1][0] + xv.y * mg[1][1] + xv.z * mg[1][2] + xv.w * mg[1][3];
                gg += beEr[2] + xv.x * mg[2][0] + xv.y * mg[2][1] + xv.z * mg[2][2] + xv.w * mg[2][3];
                go += beEr[3] + xv.x * mg[3][0] + xv.y * mg[3][1] + xv.z * mg[3][2] + xv.w * mg[3][3];
                float cn = sigm(gf) * cst[r] + sigm(gi) * tanh_(gg);
                cst[r] = cn;
                hv = sigm(go) * tanh_(cn);
            } else {
                gi += bePr[0];
                gg += bePr[2];
                go += bePr[3];
                float cn = sigm(gi) * tanh_(gg);   // zero initial state in pred phase
                hv = sigm(go) * tanh_(cn);
            }
            if (lo) my_rows[row_l * 20 + jl] = hv;   // wave-private LDS rows
        }

        // ---- pack + publish h slice via plain sc0 sc1 stores (no RMW)
        {
            const float* hp = my_rows + (l & 31) * 20 + (l >> 5) * 8;
            float4 f0 = ((const float4*)hp)[0];
            float4 f1 = ((const float4*)hp)[1];
            unsigned int w0 = (unsigned int)f2bf(f0.x) | ((unsigned int)f2bf(f0.y) << 16);
            unsigned int w1 = (unsigned int)f2bf(f0.z) | ((unsigned int)f2bf(f0.w) << 16);
            unsigned int w2 = (unsigned int)f2bf(f1.x) | ((unsigned int)f2bf(f1.y) << 16);
            unsigned int w3 = (unsigned int)f2bf(f1.z) | ((unsigned int)f2bf(f1.w) << 16);
            unsigned long long s0 = (unsigned long long)w0 | ((unsigned long long)w1 << 32);
            unsigned long long s1 = (unsigned long long)w2 | ((unsigned long long)w3 << 32);
            size_t widx = ((((size_t)(((u + 1) & 1) * 2 + branch) * 8 + rb_g) * 32 + cg) * 64 + l) * 2;
            __hip_atomic_store(hbuf + widx + 0, s0, __ATOMIC_RELAXED, __HIP_MEMORY_SCOPE_SYSTEM);
            __hip_atomic_store(hbuf + widx + 1, s1, __ATOMIC_RELAXED, __HIP_MEMORY_SCOPE_SYSTEM);
        }
        asm volatile("s_waitcnt vmcnt(0)" ::: "memory");   // h at LLC before flag
        if (l == 0)
            __hip_atomic_store(flags + chain * 32 + cg, u + 1,
                               __ATOMIC_RELAXED, __HIP_MEMORY_SCOPE_SYSTEM);

        // ---- fused decoder (after publish; off the consumer critical path)
        if (u >= 1) {
            const float* hrow = my_rows + (l & 31) * 20;
            float4 h0 = ((const float4*)hrow)[0];
            float4 h1 = ((const float4*)hrow)[1];
            float4 h2 = ((const float4*)hrow)[2];
            float4 h3 = ((const float4*)hrow)[3];
            int bg = rh * 128 + rt * 32 + (l & 31);
#pragma unroll
            for (int i = 0; i < 2; ++i) {
                int d = (l >> 5) + 2 * i;
                if (d < nf) {
                    float s = h0.x * wdr[i][0].x + h0.y * wdr[i][0].y + h0.z * wdr[i][0].z + h0.w * wdr[i][0].w
                            + h1.x * wdr[i][1].x + h1.y * wdr[i][1].y + h1.z * wdr[i][1].z + h1.w * wdr[i][1].w
                            + h2.x * wdr[i][2].x + h2.y * wdr[i][2].y + h2.z * wdr[i][2].z + h2.w * wdr[i][2].w
                            + h3.x * wdr[i][3].x + h3.y * wdr[i][3].y + h3.z * wdr[i][3].z + h3.w * wdr[i][3].w;
                    unsafeAtomicAdd(out + ((size_t)bg * NT + (u - 1)) * 7 + branch * 3 + d, s);
                }
            }
        }
    }
}

extern "C" void kernel_launch(void* const* d_in, const int* in_sizes, int n_in,
                              void* d_out, int out_size, void* d_ws, size_t ws_size,
                              hipStream_t stream) {
    const float* x          = (const float*)d_in[0];
    const float* lin_enc_w  = (const float*)d_in[1];
    const float* lin_enc_b  = (const float*)d_in[2];
    const float* quat_enc_w = (const float*)d_in[3];
    const float* quat_enc_b = (const float*)d_in[4];
    const float* lin_wih    = (const float*)d_in[5];
    const float* lin_whh    = (const float*)d_in[6];
    const float* lin_bih    = (const float*)d_in[7];
    const float* lin_bhh    = (const float*)d_in[8];
    const float* quat_wih   = (const float*)d_in[9];
    const float* quat_whh   = (const float*)d_in[10];
    const float* quat_bih   = (const float*)d_in[11];
    const float* quat_bhh   = (const float*)d_in[12];
    const float* lin_dec_w  = (const float*)d_in[13];
    const float* lin_dec_b  = (const float*)d_in[14];
    const float* quat_dec_w = (const float*)d_in[15];
    const float* quat_dec_b = (const float*)d_in[16];
    float* out = (float*)d_out;
    char* ws = (char*)d_ws;

    unsigned short* wfrag     = (unsigned short*)(ws + 0);
    unsigned long long* hbuf  = (unsigned long long*)(ws + 8388608ull);
    int* flags                = (int*)(ws + 9437184ull);
    float4* xbuf              = (float4*)(ws + 9469952ull);
    float* M                  = (float*)(ws + 12222464ull);
    float* bE                 = (float*)(ws + 12288000ull);
    float* bP                 = (float*)(ws + 12304384ull);

    static const int kDynLds = 131072 + 128 * 20 * 4;   // 141312
    hipFuncSetAttribute((const void*)k_persist,
                        hipFuncAttributeMaxDynamicSharedMemorySize, kDynLds);

    k_wfrag<<<2048, 256, 0, stream>>>(lin_whh, lin_wih, quat_whh, quat_wih, wfrag);
    k_mbias<<<16, 256, 0, stream>>>(lin_wih, quat_wih, lin_enc_w, quat_enc_w,
                                    lin_enc_b, quat_enc_b, lin_bih, lin_bhh,
                                    quat_bih, quat_bhh, M, bE, bP);
    k_xprep<<<672, 256, 0, stream>>>(x, xbuf);
    // zero hbuf (65536 int4) + flags (512 int4) contiguously
    k_zero<<<258, 256, 0, stream>>>((int4*)(ws + 8388608ull), 66048);
    k_initout<<<3017, 256, 0, stream>>>(out, lin_dec_b, quat_dec_b);

    k_persist<<<NBLK, 256, kDynLds, stream>>>(wfrag, M, bE, bP, xbuf,
                                              lin_dec_w, quat_dec_w,
                                              hbuf, out, flags);
}